// Round 1
// baseline (120.654 us; speedup 1.0000x reference)
//
#include <hip/hip_runtime.h>
#include <math.h>

#define NQ      12
#define DIM     4096
#define LAYERS  8
#define FEAT    3072
#define NCLASS  10
#define STRIDE  66   // padded LDS row stride (floats). f(i) = (i>>6) + STRIDE*(i&63)

// prefix-xor (inverse Gray) of a 6-bit value; folds to a constant for unrolled r
__device__ __forceinline__ int px6c(int r) {
    int u = r ^ (r >> 1); u ^= u >> 2; u ^= u >> 4; return u;
}

__global__ __launch_bounds__(64)
void qnn_kernel(const float* __restrict__ x,
                const float* __restrict__ ang,
                const float* __restrict__ W,
                const float* __restrict__ bias,
                float* __restrict__ out)
{
    __shared__ float lds[STRIDE * 64];      // 16896 B
    __shared__ float cst[LAYERS * NQ];      // cos table (96)
    __shared__ float snt[LAYERS * NQ];      // sin table (96)

    const int t = threadIdx.x;              // 0..63 (one wave per block/state)
    const int b = blockIdx.x;

    // ---- trig tables (96 angles) ----
    {
        float a0 = ang[t];
        cst[t] = cosf(a0);
        snt[t] = sinf(a0);
        if (t < LAYERS * NQ - 64) {         // t < 32
            float a1 = ang[64 + t];
            cst[64 + t] = cosf(a1);
            snt[64 + t] = sinf(a1);
        }
    }

    // ---- load psi0 (unnormalized) in A-layout: v[r] = psi[64*t + r] ----
    float v[64];
    {
        const float* xr = x + (size_t)b * FEAT + 64 * t;
        if (t < FEAT / 64) {                // t < 48: real features
#pragma unroll
            for (int r = 0; r < 64; r += 4) {
                float4 f4 = *(const float4*)(xr + r);
                v[r] = f4.x; v[r + 1] = f4.y; v[r + 2] = f4.z; v[r + 3] = f4.w;
            }
        } else {                            // zero pad 3072..4095
#pragma unroll
            for (int r = 0; r < 64; ++r) v[r] = 0.f;
        }
    }

    // ---- ||x||^2 (normalization deferred to epilogue: circuit is linear) ----
    float ss = 0.f;
#pragma unroll
    for (int r = 0; r < 64; ++r) ss = fmaf(v[r], v[r], ss);
#pragma unroll
    for (int o = 1; o < 64; o <<= 1) ss += __shfl_xor(ss, o, 64);
    const float invn2 = 1.0f / ss;

    // per-lane helpers for the Gray-permutation-folded reads
    int px = t ^ (t >> 1); px ^= px >> 2; px ^= px >> 4;   // px6(t)
    const int flip = (px & 1) ? 63 : 0;                    // parity(t) ? 63 : 0

    __syncthreads();   // tables ready; also fences lds for layer 0

#pragma unroll 1
    for (int l = 0; l < LAYERS; ++l) {
        const float* cl = cst + l * NQ;
        const float* sl = snt + l * NQ;

        // ---- phase A: reg bit p == index bit p -> qubit (11-p) ----
#pragma unroll
        for (int p = 0; p < 6; ++p) {
            const float c = cl[11 - p], s = sl[11 - p];
#pragma unroll
            for (int r0 = 0; r0 < 64; ++r0) {
                if (r0 & (1 << p)) continue;
                const int r1 = r0 | (1 << p);
                const float a = v[r0], e = v[r1];
                v[r0] = c * a - s * e;
                v[r1] = s * a + c * e;
            }
        }

        // ---- A -> LDS: i = 64t + r at f = t + STRIDE*r (consecutive lanes: conflict-free) ----
#pragma unroll
        for (int r = 0; r < 64; ++r) lds[t + STRIDE * r] = v[r];
        __syncthreads();

        // ---- LDS -> B: v[r] = psi[64r + t] at f = r + STRIDE*t (b64, 2-way max) ----
#pragma unroll
        for (int r = 0; r < 64; r += 2) {
            const float2 f2 = *(const float2*)(lds + STRIDE * t + r);
            v[r] = f2.x; v[r + 1] = f2.y;
        }

        // ---- phase B: reg bit p == index bit (6+p) -> qubit (5-p) ----
#pragma unroll
        for (int p = 0; p < 6; ++p) {
            const float c = cl[5 - p], s = sl[5 - p];
#pragma unroll
            for (int r0 = 0; r0 < 64; ++r0) {
                if (r0 & (1 << p)) continue;
                const int r1 = r0 | (1 << p);
                const float a = v[r0], e = v[r1];
                v[r0] = c * a - s * e;
                v[r1] = s * a + c * e;
            }
        }

        if (l == LAYERS - 1) break;  // last layer: Gray perm folds into W gather

        // ---- B -> LDS (own-lane addresses, no cross-lane hazard before this) ----
#pragma unroll
        for (int r = 0; r < 64; r += 2) {
            float2 f2; f2.x = v[r]; f2.y = v[r + 1];
            *(float2*)(lds + STRIDE * t + r) = f2;
        }
        __syncthreads();

        // ---- LDS -> A with CNOT-cascade (Gray) perm folded:
        //      v[r] = psi[ginv(64t + r)],  ginv = prefix-xor
        //      addr = px6(t) + STRIDE*(px6(r) ^ (parity(t)?63:0))  [2-way banks] ----
#pragma unroll
        for (int r = 0; r < 64; ++r) {
            v[r] = lds[px + STRIDE * (px6c(r) ^ flip)];
        }
        __syncthreads();  // fence before next layer's A->LDS overwrite
    }

    // ---- epilogue: out[c] = invn2 * sum_j psi[j]^2 * W[c, g(j)] + bias[c]
    //      (in B layout: j = 64r + t; g(j) = 64*gray6(r) + (gray6(t) ^ ((r&1)<<5))) ----
    const int gt = t ^ (t >> 1);

    float acc[NCLASS];
#pragma unroll
    for (int c = 0; c < NCLASS; ++c) acc[c] = 0.f;

#pragma unroll
    for (int r = 0; r < 64; ++r) {
        const int gr = r ^ (r >> 1);
        const int col = 64 * gr + (gt ^ ((r & 1) << 5));
        const float p = v[r] * v[r];
        const float* wp = W + col;
#pragma unroll
        for (int c = 0; c < NCLASS; ++c)
            acc[c] = fmaf(p, wp[c * DIM], acc[c]);
    }

#pragma unroll
    for (int c = 0; c < NCLASS; ++c) {
        float a = acc[c];
#pragma unroll
        for (int o = 1; o < 64; o <<= 1) a += __shfl_xor(a, o, 64);
        acc[c] = a;
    }

    if (t == 0) {
#pragma unroll
        for (int c = 0; c < NCLASS; ++c)
            out[b * NCLASS + c] = fmaf(acc[c], invn2, bias[c]);
    }
}

extern "C" void kernel_launch(void* const* d_in, const int* in_sizes, int n_in,
                              void* d_out, int out_size, void* d_ws, size_t ws_size,
                              hipStream_t stream) {
    const float* x    = (const float*)d_in[0];
    const float* ang  = (const float*)d_in[1];
    const float* W    = (const float*)d_in[2];
    const float* bias = (const float*)d_in[3];
    float* out = (float*)d_out;
    const int batch = in_sizes[0] / FEAT;   // 2048
    qnn_kernel<<<batch, 64, 0, stream>>>(x, ang, W, bias, out);
}